// Round 8
// baseline (479.384 us; speedup 1.0000x reference)
//
#include <hip/hip_runtime.h>
#include <hip/hip_bf16.h>
#include <math.h>

// GAT 2-layer fused pipeline for MI355X (gfx950).
// Dims per reference: D_IN=D_H=128, D_OUT=64, SLOPE=0.2.
//
// Round-8:
//  - gat_agg gathers p as bf16 (packed dword / ushort per lane): halves the
//    190 MB HBM fetch that bounded r7's 59us gat1. q stays fp32.
//  - mfma_gemm split into gridDim.y pieces (32 KB W slice per block, single
//    pass): 392-784 blocks vs r7's 196 2-pass (under-occupancy + serial).
//    Epilogues: q->fp32, p->bf16, m1/m2->hi/lo packed.
//  - cursor zeroing folded into pack_w; 3 scans fused into one single-block
//    scan. 12 -> 9 dispatches.

#define SLOPE 0.2f

typedef __attribute__((ext_vector_type(8))) __bf16 bf16x8;
typedef __attribute__((ext_vector_type(4))) float f32x4;

__device__ __forceinline__ float gelu_erf(float x) {
    return 0.5f * x * (1.0f + erff(x * 0.70710678118654752f));
}

__device__ __forceinline__ unsigned short f2bf(float f) {  // RNE
    unsigned int u = __float_as_uint(f);
    return (unsigned short)((u + 0x7fffu + ((u >> 16) & 1u)) >> 16);
}
__device__ __forceinline__ float bf2f(unsigned short h) {
    return __uint_as_float((unsigned int)h << 16);
}

// Full-wave (64-lane) f32 sum via DPP; result broadcast via readlane 63.
__device__ __forceinline__ float wave_sum_bcast(float x) {
    x += __int_as_float(__builtin_amdgcn_update_dpp(0, __float_as_int(x), 0x111, 0xF, 0xF, true));
    x += __int_as_float(__builtin_amdgcn_update_dpp(0, __float_as_int(x), 0x112, 0xF, 0xF, true));
    x += __int_as_float(__builtin_amdgcn_update_dpp(0, __float_as_int(x), 0x114, 0xF, 0xF, true));
    x += __int_as_float(__builtin_amdgcn_update_dpp(0, __float_as_int(x), 0x118, 0xF, 0xF, true));
    x += __int_as_float(__builtin_amdgcn_update_dpp(0, __float_as_int(x), 0x142, 0xF, 0xF, true));
    x += __int_as_float(__builtin_amdgcn_update_dpp(0, __float_as_int(x), 0x143, 0xF, 0xF, true));
    return __int_as_float(__builtin_amdgcn_readlane(__float_as_int(x), 63));
}

// ---------------- weight prepack + cursor zero -------------------------------
// Pack index i = ((ct*4+ks)*64 + lane)*8 + j  ->  W[k][n],
// k = ks*32 + (lane>>4)*8 + j,  n = ct*16 + (lane&15).  hi at [i], lo at [CE+i].
__global__ __launch_bounds__(256) void pack_w(
    const float* __restrict__ W0,  const float* __restrict__ Wq1,
    const float* __restrict__ Wp1, const float* __restrict__ Wq2,
    const float* __restrict__ Wp2,
    unsigned short* __restrict__ P0,  unsigned short* __restrict__ Pq1,
    unsigned short* __restrict__ Pp1, unsigned short* __restrict__ Pq2,
    unsigned short* __restrict__ Pp2,
    int* __restrict__ cursor, int N)
{
    if (blockIdx.y == 5) {   // zero the histogram counters
        for (int i = blockIdx.x * 256 + threadIdx.x; i < N; i += 64 * 256)
            cursor[i] = 0;
        return;
    }
    const float* W; unsigned short* P; int C;
    switch (blockIdx.y) {
        case 0:  W = W0;  P = P0;  C = 128; break;
        case 1:  W = Wq1; P = Pq1; C = 128; break;
        case 2:  W = Wp1; P = Pp1; C = 128; break;
        case 3:  W = Wq2; P = Pq2; C = 64;  break;
        default: W = Wp2; P = Pp2; C = 64;  break;
    }
    int i = blockIdx.x * 256 + threadIdx.x;
    int CE = C * 128;
    if (i >= CE) return;
    int j = i & 7, l = (i >> 3) & 63, ks = (i >> 9) & 3, ct = i >> 11;
    int k = ks * 32 + ((l >> 4) << 3) + j;
    int n = ct * 16 + (l & 15);
    float v = W[k * C + n];
    unsigned short hb = f2bf(v);
    P[i] = hb;
    P[CE + i] = f2bf(v - bf2f(hb));
}

// ---------------- MFMA GEMM -------------------------------------------------
// out[N,C] = act(A[N,128] @ W[128,C] + bias); block = 256 rows x 64 cols.
// gridDim.y pieces; each stages a 32 KB W slice (4 col-tiles, hi+lo) in LDS.
// EPI 0: out = gelu -> hi/lo packed bf16 (layer 0).
// EPI 1: piece wsel==0 -> q fp32; wsel==1 -> p bf16.
template <int C, int PIECES, int EPI>
__global__ __launch_bounds__(256) void mfma_gemm(
    const float* __restrict__ Af,
    const unsigned short* __restrict__ AHg, const unsigned short* __restrict__ ALg,
    const unsigned short* __restrict__ P1, const float* __restrict__ b1,
    const unsigned short* __restrict__ P2, const float* __restrict__ b2,
    float* __restrict__ outq, unsigned short* __restrict__ outp,
    unsigned short* __restrict__ o1hi, unsigned short* __restrict__ o1lo,
    int N)
{
    constexpr bool AF32 = (EPI == 0);
    constexpr int CE = C * 128;
    constexpr int RF = 4;

    int wsel, ct0;
    if constexpr (PIECES == 4)      { wsel = blockIdx.y >> 1; ct0 = (blockIdx.y & 1) * 4; }
    else if constexpr (C == 128)    { wsel = 0; ct0 = blockIdx.y * 4; }
    else                            { wsel = blockIdx.y; ct0 = 0; }

    const unsigned short* Pw = wsel ? P2 : P1;
    const float* bb = wsel ? b2 : b1;
    const unsigned short* Whi = Pw + ct0 * 2048;
    const unsigned short* Wlo = Pw + CE + ct0 * 2048;

    __shared__ __align__(16) unsigned short Blds[16384];  // 4 ct x (hi+lo) = 32 KB

    const int t = threadIdx.x;
    const int lane = t & 63;
    const int w = t >> 6;
    const int row0 = blockIdx.x * 256 + w * 64;
    const int mcol = lane & 15;
    const int koff = (lane >> 4) * 8;

#pragma unroll
    for (int i = 0; i < 4; i++) {
        int idx = (t + i * 256) * 8;
        *reinterpret_cast<uint4*>(&Blds[idx]) = *reinterpret_cast<const uint4*>(&Whi[idx]);
        *reinterpret_cast<uint4*>(&Blds[8192 + idx]) = *reinterpret_cast<const uint4*>(&Wlo[idx]);
    }

    auto loadA = [&](int ks, bf16x8* ah, bf16x8* al) {
#pragma unroll
        for (int rf = 0; rf < RF; rf++) {
            int gr = row0 + rf * 16 + mcol;
            if (AF32) {
                float4 v0 = make_float4(0.f, 0.f, 0.f, 0.f), v1 = v0;
                if (gr < N) {
                    const float* ap = Af + (size_t)gr * 128 + ks * 32 + koff;
                    v0 = *reinterpret_cast<const float4*>(ap);
                    v1 = *reinterpret_cast<const float4*>(ap + 4);
                }
                union { bf16x8 v; unsigned short u[8]; } H, L;
                const float* f0 = reinterpret_cast<const float*>(&v0);
                const float* f1 = reinterpret_cast<const float*>(&v1);
#pragma unroll
                for (int j = 0; j < 4; j++) {
                    unsigned short hb = f2bf(f0[j]);
                    H.u[j] = hb; L.u[j] = f2bf(f0[j] - bf2f(hb));
                    unsigned short hb2 = f2bf(f1[j]);
                    H.u[4 + j] = hb2; L.u[4 + j] = f2bf(f1[j] - bf2f(hb2));
                }
                ah[rf] = H.v; al[rf] = L.v;
            } else {
                union { bf16x8 v; uint4 q; } HH, LL;
                HH.q = make_uint4(0, 0, 0, 0); LL.q = HH.q;
                if (gr < N) {
                    size_t off = (size_t)gr * 128 + ks * 32 + koff;
                    HH.q = *reinterpret_cast<const uint4*>(AHg + off);
                    LL.q = *reinterpret_cast<const uint4*>(ALg + off);
                }
                ah[rf] = HH.v; al[rf] = LL.v;
            }
        }
    };

    f32x4 acc[4][RF];
#pragma unroll
    for (int c = 0; c < 4; c++)
#pragma unroll
        for (int r = 0; r < RF; r++) acc[c][r] = (f32x4){0.f, 0.f, 0.f, 0.f};

    bf16x8 ahA[RF], alA[RF], ahB[RF], alB[RF];
    loadA(0, ahA, alA);
    __syncthreads();   // W slice visible

#pragma unroll
    for (int ks = 0; ks < 4; ks++) {
        bf16x8* ah = (ks & 1) ? ahB : ahA;
        bf16x8* al = (ks & 1) ? alB : alA;
        if (ks < 3) loadA(ks + 1, (ks & 1) ? ahA : ahB, (ks & 1) ? alA : alB);
#pragma unroll
        for (int ct = 0; ct < 4; ct++) {
            int off = (ct * 4 + ks) * 512 + lane * 8;
            bf16x8 bh = *reinterpret_cast<const bf16x8*>(&Blds[off]);
            bf16x8 bl = *reinterpret_cast<const bf16x8*>(&Blds[8192 + off]);
#pragma unroll
            for (int rf = 0; rf < RF; rf++) {
                acc[ct][rf] = __builtin_amdgcn_mfma_f32_16x16x32_bf16(ah[rf], bh, acc[ct][rf], 0, 0, 0);
                acc[ct][rf] = __builtin_amdgcn_mfma_f32_16x16x32_bf16(al[rf], bh, acc[ct][rf], 0, 0, 0);
                acc[ct][rf] = __builtin_amdgcn_mfma_f32_16x16x32_bf16(ah[rf], bl, acc[ct][rf], 0, 0, 0);
            }
        }
    }

    // epilogue: C/D layout col=lane&15, row=(lane>>4)*4+reg
#pragma unroll
    for (int ct = 0; ct < 4; ct++) {
        int col = (ct0 + ct) * 16 + mcol;
        float bv = bb[col];
#pragma unroll
        for (int rf = 0; rf < RF; rf++) {
#pragma unroll
            for (int r = 0; r < 4; r++) {
                int gr = row0 + rf * 16 + (lane >> 4) * 4 + r;
                if (gr >= N) continue;
                float v = acc[ct][rf][r] + bv;
                if (EPI == 0) {
                    v = gelu_erf(v);
                    unsigned short hb = f2bf(v);
                    o1hi[(size_t)gr * C + col] = hb;
                    o1lo[(size_t)gr * C + col] = f2bf(v - bf2f(hb));
                } else {
                    if (wsel == 0) outq[(size_t)gr * C + col] = v;
                    else           outp[(size_t)gr * C + col] = f2bf(v);
                }
            }
        }
    }
}

// ---------------- CSR build --------------------------------------------------
__global__ __launch_bounds__(256) void hist_kernel(const int* __restrict__ dst,
                                                   int* __restrict__ cnt, int E)
{
    int i = blockIdx.x * 256 + threadIdx.x;
    if (i < E) atomicAdd(&cnt[dst[i]], 1);
}

// single-block exclusive scan of cursor[N] -> offs/cursor; offs[N]=E.
__global__ __launch_bounds__(1024) void scan_kernel(int* __restrict__ cursor,
                                                    int* __restrict__ offs,
                                                    int N, int E)
{
    __shared__ int lds[1024];
    const int t = threadIdx.x;
    const int chunk = (N + 1023) >> 10;
    const int base = t * chunk;
    int s = 0;
    for (int j = 0; j < chunk; j++) {
        int i = base + j;
        if (i < N) s += cursor[i];
    }
    lds[t] = s;
    __syncthreads();
    int x = s;
    for (int off = 1; off < 1024; off <<= 1) {
        int y = (t >= off) ? lds[t - off] : 0;
        __syncthreads();
        x += y;
        lds[t] = x;
        __syncthreads();
    }
    int run = x - s;   // exclusive over chunks
    for (int j = 0; j < chunk; j++) {
        int i = base + j;
        if (i >= N) break;
        int c = cursor[i];
        offs[i] = run;
        cursor[i] = run;
        run += c;
    }
    if (t == 0) offs[N] = E;
}

__global__ __launch_bounds__(256) void scatter_kernel(const int* __restrict__ src,
                                                      const int* __restrict__ dst,
                                                      int* __restrict__ cursor,
                                                      int* __restrict__ csr_src, int E)
{
    int i = blockIdx.x * 256 + threadIdx.x;
    if (i < E) {
        int d = dst[i];
        int pos = atomicAdd(&cursor[d], 1);
        csr_src[pos] = src[i];
    }
}

// ---------------- fused GAT edge-softmax + aggregation -----------------------
// One wave per dst node (wave-uniform via readfirstlane -> scalar CSR walk).
// p is bf16: D=128 -> packed dword per lane (dims 2*lane, 2*lane+1);
//            D=64  -> ushort per lane.
// EPI 0 (D=128): m2 = gelu(h+bvec) packed hi/lo bf16.  EPI 1 (D=64): fp32 out.
template <int D, int EPI>
__global__ __launch_bounds__(256) void gat_agg(
    const float* __restrict__ q, const void* __restrict__ pv_,
    const float* __restrict__ a, const float* __restrict__ bvec,
    const int* __restrict__ offs, const int* __restrict__ csr_src,
    float* __restrict__ out, unsigned int* __restrict__ mhi,
    unsigned int* __restrict__ mlo, int N)
{
    constexpr int VPL = D / 64;  // 2 (D=128) or 1 (D=64)
    const int lane = threadIdx.x & 63;
    const int node = __builtin_amdgcn_readfirstlane(blockIdx.x * 4 + (threadIdx.x >> 6));
    if (node >= N) return;  // scalar branch

    const unsigned int* pp32 = (const unsigned int*)pv_;
    const unsigned short* pp16 = (const unsigned short*)pv_;

    float qv[VPL], av[VPL], acc[VPL];
#pragma unroll
    for (int v = 0; v < VPL; v++) {
        qv[v] = q[(size_t)node * D + lane * VPL + v];
        av[v] = a[lane * VPL + v];
        acc[v] = 0.f;
    }
    float denom = 0.f;

    const int e0 = offs[node], e1 = offs[node + 1];
    int e = e0;

    for (; e + 4 <= e1; e += 4) {
        int s0 = csr_src[e + 0];
        int s1 = csr_src[e + 1];
        int s2 = csr_src[e + 2];
        int s3 = csr_src[e + 3];
        float pv0[VPL], pv1[VPL], pv2[VPL], pv3[VPL];
        if (VPL == 2) {
            unsigned int u0 = pp32[(size_t)s0 * 64 + lane];
            unsigned int u1 = pp32[(size_t)s1 * 64 + lane];
            unsigned int u2 = pp32[(size_t)s2 * 64 + lane];
            unsigned int u3 = pp32[(size_t)s3 * 64 + lane];
            pv0[0] = __uint_as_float(u0 << 16); pv0[1] = __uint_as_float(u0 & 0xffff0000u);
            pv1[0] = __uint_as_float(u1 << 16); pv1[1] = __uint_as_float(u1 & 0xffff0000u);
            pv2[0] = __uint_as_float(u2 << 16); pv2[1] = __uint_as_float(u2 & 0xffff0000u);
            pv3[0] = __uint_as_float(u3 << 16); pv3[1] = __uint_as_float(u3 & 0xffff0000u);
        } else {
            pv0[0] = bf2f(pp16[(size_t)s0 * 64 + lane]);
            pv1[0] = bf2f(pp16[(size_t)s1 * 64 + lane]);
            pv2[0] = bf2f(pp16[(size_t)s2 * 64 + lane]);
            pv3[0] = bf2f(pp16[(size_t)s3 * 64 + lane]);
        }
        float pa0 = 0.f, pa1 = 0.f, pa2 = 0.f, pa3 = 0.f;
#pragma unroll
        for (int v = 0; v < VPL; v++) {
            float t0 = qv[v] + pv0[v];
            float t1 = qv[v] + pv1[v];
            float t2 = qv[v] + pv2[v];
            float t3 = qv[v] + pv3[v];
            t0 = fmaxf(t0, SLOPE * t0);
            t1 = fmaxf(t1, SLOPE * t1);
            t2 = fmaxf(t2, SLOPE * t2);
            t3 = fmaxf(t3, SLOPE * t3);
            pa0 = fmaf(t0, av[v], pa0);
            pa1 = fmaf(t1, av[v], pa1);
            pa2 = fmaf(t2, av[v], pa2);
            pa3 = fmaf(t3, av[v], pa3);
        }
        float w0 = wave_sum_bcast(pa0);
        float w1 = wave_sum_bcast(pa1);
        float w2 = wave_sum_bcast(pa2);
        float w3 = wave_sum_bcast(pa3);
        float es0 = __expf(w0);
        float es1 = __expf(w1);
        float es2 = __expf(w2);
        float es3 = __expf(w3);
        denom += (es0 + es1) + (es2 + es3);
#pragma unroll
        for (int v = 0; v < VPL; v++) {
            acc[v] = fmaf(es0, pv0[v], acc[v]);
            acc[v] = fmaf(es1, pv1[v], acc[v]);
            acc[v] = fmaf(es2, pv2[v], acc[v]);
            acc[v] = fmaf(es3, pv3[v], acc[v]);
        }
    }
    for (; e < e1; e++) {
        int s0 = csr_src[e];
        float pv0[VPL];
        if (VPL == 2) {
            unsigned int u0 = pp32[(size_t)s0 * 64 + lane];
            pv0[0] = __uint_as_float(u0 << 16);
            pv0[1] = __uint_as_float(u0 & 0xffff0000u);
        } else {
            pv0[0] = bf2f(pp16[(size_t)s0 * 64 + lane]);
        }
        float pa0 = 0.f;
#pragma unroll
        for (int v = 0; v < VPL; v++) {
            float t0 = qv[v] + pv0[v];
            t0 = fmaxf(t0, SLOPE * t0);
            pa0 = fmaf(t0, av[v], pa0);
        }
        float es0 = __expf(wave_sum_bcast(pa0));
        denom += es0;
#pragma unroll
        for (int v = 0; v < VPL; v++)
            acc[v] = fmaf(es0, pv0[v], acc[v]);
    }

    float inv = (denom != 0.f) ? 1.f / denom : 0.f;  // zero-degree -> agg = 0
    if (EPI == 0) {
        float g0 = gelu_erf(acc[0] * inv + bvec[lane * 2 + 0]);
        float g1 = gelu_erf(acc[1] * inv + bvec[lane * 2 + 1]);
        unsigned short h0 = f2bf(g0), h1 = f2bf(g1);
        unsigned short l0 = f2bf(g0 - bf2f(h0)), l1 = f2bf(g1 - bf2f(h1));
        mhi[(size_t)node * 64 + lane] = (unsigned int)h0 | ((unsigned int)h1 << 16);
        mlo[(size_t)node * 64 + lane] = (unsigned int)l0 | ((unsigned int)l1 << 16);
    } else {
        out[(size_t)node * D + lane] = acc[0] * inv + bvec[lane];
    }
}

// ---------------- launch ------------------------------------------------------
extern "C" void kernel_launch(void* const* d_in, const int* in_sizes, int n_in,
                              void* d_out, int out_size, void* d_ws, size_t ws_size,
                              hipStream_t stream)
{
    const float* x     = (const float*)d_in[0];
    const float* W0    = (const float*)d_in[1];
    const float* b0    = (const float*)d_in[2];
    const float* Wq1   = (const float*)d_in[3];
    const float* bq1   = (const float*)d_in[4];
    const float* Wp1   = (const float*)d_in[5];
    const float* bp1   = (const float*)d_in[6];
    const float* a1    = (const float*)d_in[7];
    const float* bg2   = (const float*)d_in[8];
    const float* Wq2   = (const float*)d_in[9];
    const float* bq2   = (const float*)d_in[10];
    const float* Wp2   = (const float*)d_in[11];
    const float* bp2   = (const float*)d_in[12];
    const float* a2    = (const float*)d_in[13];
    const float* b_out = (const float*)d_in[14];
    const int*   src   = (const int*)d_in[15];
    const int*   dst   = (const int*)d_in[16];

    const int N = in_sizes[0] / 128;
    const int E = in_sizes[15];
    float* out = (float*)d_out;

    // workspace carve
    float* q_buf        = (float*)d_ws;                      // N*128 f32
    unsigned short* pb  = (unsigned short*)(q_buf + (size_t)N * 128);  // N*128 bf16
    unsigned short* Mhi = pb + (size_t)N * 128;
    unsigned short* Mlo = Mhi + (size_t)N * 128;
    unsigned short* P0  = Mlo + (size_t)N * 128;
    unsigned short* Pq1 = P0  + 128 * 128 * 2;
    unsigned short* Pp1 = Pq1 + 128 * 128 * 2;
    unsigned short* Pq2 = Pp1 + 128 * 128 * 2;
    unsigned short* Pp2 = Pq2 + 128 * 64 * 2;
    int* offs    = (int*)(Pp2 + 128 * 64 * 2);
    int* cursor  = offs + (N + 1);
    int* csr_src = cursor + N;

    // 1) weight prepack + cursor zero
    pack_w<<<dim3(64, 6), 256, 0, stream>>>(W0, Wq1, Wp1, Wq2, Wp2,
                                            P0, Pq1, Pp1, Pq2, Pp2, cursor, N);
    // 2-4) CSR build
    hist_kernel<<<(E + 255) / 256, 256, 0, stream>>>(dst, cursor, E);
    scan_kernel<<<1, 1024, 0, stream>>>(cursor, offs, N, E);
    scatter_kernel<<<(E + 255) / 256, 256, 0, stream>>>(src, dst, cursor, csr_src, E);

    const int GB = (N + 255) / 256;

    // 5) layer 0: m1 = gelu(x@W0 + b0) -> Mhi/Mlo
    mfma_gemm<128, 2, 0><<<dim3(GB, 2), 256, 0, stream>>>(
        x, nullptr, nullptr, P0, b0, nullptr, nullptr,
        nullptr, nullptr, Mhi, Mlo, N);
    // 6) layer 1 projections: q1 fp32, p1 bf16
    mfma_gemm<128, 4, 1><<<dim3(GB, 4), 256, 0, stream>>>(
        nullptr, Mhi, Mlo, Pq1, bq1, Pp1, bp1,
        q_buf, pb, nullptr, nullptr, N);
    // 7) layer 1 GAT -> m2 = gelu(h1 + bg2) -> Mhi/Mlo
    gat_agg<128, 0><<<(N + 3) / 4, 256, 0, stream>>>(
        q_buf, pb, a1, bg2, offs, csr_src,
        nullptr, (unsigned int*)Mhi, (unsigned int*)Mlo, N);
    // 8) layer 2 projections: q2 fp32, p2 bf16
    mfma_gemm<64, 2, 1><<<dim3(GB, 2), 256, 0, stream>>>(
        nullptr, Mhi, Mlo, Pq2, bq2, Pp2, bp2,
        q_buf, pb, nullptr, nullptr, N);
    // 9) layer 2 GAT + b_out -> d_out
    gat_agg<64, 1><<<(N + 3) / 4, 256, 0, stream>>>(
        q_buf, pb, a2, b_out, offs, csr_src,
        out, nullptr, nullptr, N);
}

// Round 9
// 371.998 us; speedup vs baseline: 1.2887x; 1.2887x over previous
//
#include <hip/hip_runtime.h>
#include <hip/hip_bf16.h>
#include <math.h>

// GAT 2-layer fused pipeline for MI355X (gfx950).
// Dims per reference: D_IN=D_H=128, D_OUT=64, SLOPE=0.2.
//
// Round-9: revert r8's fused single-block scan (126us: 1 CU, serial
// dependent load-store chunks) back to the r7 hierarchical 3-kernel scan
// (196 parallel blocks, <10us). Everything else = round 8:
//  - gat_agg gathers p as bf16; q fp32; scalar CSR walk; x4 unroll; DPP.
//  - mfma_gemm split-precision bf16 MFMA, W slice (32 KB) LDS-resident,
//    gridDim.y pieces; activations hi/lo packed between layers.

#define SLOPE 0.2f

typedef __attribute__((ext_vector_type(8))) __bf16 bf16x8;
typedef __attribute__((ext_vector_type(4))) float f32x4;

__device__ __forceinline__ float gelu_erf(float x) {
    return 0.5f * x * (1.0f + erff(x * 0.70710678118654752f));
}

__device__ __forceinline__ unsigned short f2bf(float f) {  // RNE
    unsigned int u = __float_as_uint(f);
    return (unsigned short)((u + 0x7fffu + ((u >> 16) & 1u)) >> 16);
}
__device__ __forceinline__ float bf2f(unsigned short h) {
    return __uint_as_float((unsigned int)h << 16);
}

// Full-wave (64-lane) f32 sum via DPP; result broadcast via readlane 63.
__device__ __forceinline__ float wave_sum_bcast(float x) {
    x += __int_as_float(__builtin_amdgcn_update_dpp(0, __float_as_int(x), 0x111, 0xF, 0xF, true));
    x += __int_as_float(__builtin_amdgcn_update_dpp(0, __float_as_int(x), 0x112, 0xF, 0xF, true));
    x += __int_as_float(__builtin_amdgcn_update_dpp(0, __float_as_int(x), 0x114, 0xF, 0xF, true));
    x += __int_as_float(__builtin_amdgcn_update_dpp(0, __float_as_int(x), 0x118, 0xF, 0xF, true));
    x += __int_as_float(__builtin_amdgcn_update_dpp(0, __float_as_int(x), 0x142, 0xF, 0xF, true));
    x += __int_as_float(__builtin_amdgcn_update_dpp(0, __float_as_int(x), 0x143, 0xF, 0xF, true));
    return __int_as_float(__builtin_amdgcn_readlane(__float_as_int(x), 63));
}

// ---------------- weight prepack + cursor zero -------------------------------
// Pack index i = ((ct*4+ks)*64 + lane)*8 + j  ->  W[k][n],
// k = ks*32 + (lane>>4)*8 + j,  n = ct*16 + (lane&15).  hi at [i], lo at [CE+i].
__global__ __launch_bounds__(256) void pack_w(
    const float* __restrict__ W0,  const float* __restrict__ Wq1,
    const float* __restrict__ Wp1, const float* __restrict__ Wq2,
    const float* __restrict__ Wp2,
    unsigned short* __restrict__ P0,  unsigned short* __restrict__ Pq1,
    unsigned short* __restrict__ Pp1, unsigned short* __restrict__ Pq2,
    unsigned short* __restrict__ Pp2,
    int* __restrict__ cursor, int N)
{
    if (blockIdx.y == 5) {   // zero the histogram counters
        for (int i = blockIdx.x * 256 + threadIdx.x; i < N; i += 64 * 256)
            cursor[i] = 0;
        return;
    }
    const float* W; unsigned short* P; int C;
    switch (blockIdx.y) {
        case 0:  W = W0;  P = P0;  C = 128; break;
        case 1:  W = Wq1; P = Pq1; C = 128; break;
        case 2:  W = Wp1; P = Pp1; C = 128; break;
        case 3:  W = Wq2; P = Pq2; C = 64;  break;
        default: W = Wp2; P = Pp2; C = 64;  break;
    }
    int i = blockIdx.x * 256 + threadIdx.x;
    int CE = C * 128;
    if (i >= CE) return;
    int j = i & 7, l = (i >> 3) & 63, ks = (i >> 9) & 3, ct = i >> 11;
    int k = ks * 32 + ((l >> 4) << 3) + j;
    int n = ct * 16 + (l & 15);
    float v = W[k * C + n];
    unsigned short hb = f2bf(v);
    P[i] = hb;
    P[CE + i] = f2bf(v - bf2f(hb));
}

// ---------------- MFMA GEMM -------------------------------------------------
// out[N,C] = act(A[N,128] @ W[128,C] + bias); block = 256 rows x 64 cols.
// gridDim.y pieces; each stages a 32 KB W slice (4 col-tiles, hi+lo) in LDS.
// EPI 0: out = gelu -> hi/lo packed bf16 (layer 0).
// EPI 1: piece wsel==0 -> q fp32; wsel==1 -> p bf16.
template <int C, int PIECES, int EPI>
__global__ __launch_bounds__(256) void mfma_gemm(
    const float* __restrict__ Af,
    const unsigned short* __restrict__ AHg, const unsigned short* __restrict__ ALg,
    const unsigned short* __restrict__ P1, const float* __restrict__ b1,
    const unsigned short* __restrict__ P2, const float* __restrict__ b2,
    float* __restrict__ outq, unsigned short* __restrict__ outp,
    unsigned short* __restrict__ o1hi, unsigned short* __restrict__ o1lo,
    int N)
{
    constexpr bool AF32 = (EPI == 0);
    constexpr int CE = C * 128;
    constexpr int RF = 4;

    int wsel, ct0;
    if constexpr (PIECES == 4)      { wsel = blockIdx.y >> 1; ct0 = (blockIdx.y & 1) * 4; }
    else if constexpr (C == 128)    { wsel = 0; ct0 = blockIdx.y * 4; }
    else                            { wsel = blockIdx.y; ct0 = 0; }

    const unsigned short* Pw = wsel ? P2 : P1;
    const float* bb = wsel ? b2 : b1;
    const unsigned short* Whi = Pw + ct0 * 2048;
    const unsigned short* Wlo = Pw + CE + ct0 * 2048;

    __shared__ __align__(16) unsigned short Blds[16384];  // 4 ct x (hi+lo) = 32 KB

    const int t = threadIdx.x;
    const int lane = t & 63;
    const int w = t >> 6;
    const int row0 = blockIdx.x * 256 + w * 64;
    const int mcol = lane & 15;
    const int koff = (lane >> 4) * 8;

#pragma unroll
    for (int i = 0; i < 4; i++) {
        int idx = (t + i * 256) * 8;
        *reinterpret_cast<uint4*>(&Blds[idx]) = *reinterpret_cast<const uint4*>(&Whi[idx]);
        *reinterpret_cast<uint4*>(&Blds[8192 + idx]) = *reinterpret_cast<const uint4*>(&Wlo[idx]);
    }

    auto loadA = [&](int ks, bf16x8* ah, bf16x8* al) {
#pragma unroll
        for (int rf = 0; rf < RF; rf++) {
            int gr = row0 + rf * 16 + mcol;
            if (AF32) {
                float4 v0 = make_float4(0.f, 0.f, 0.f, 0.f), v1 = v0;
                if (gr < N) {
                    const float* ap = Af + (size_t)gr * 128 + ks * 32 + koff;
                    v0 = *reinterpret_cast<const float4*>(ap);
                    v1 = *reinterpret_cast<const float4*>(ap + 4);
                }
                union { bf16x8 v; unsigned short u[8]; } H, L;
                const float* f0 = reinterpret_cast<const float*>(&v0);
                const float* f1 = reinterpret_cast<const float*>(&v1);
#pragma unroll
                for (int j = 0; j < 4; j++) {
                    unsigned short hb = f2bf(f0[j]);
                    H.u[j] = hb; L.u[j] = f2bf(f0[j] - bf2f(hb));
                    unsigned short hb2 = f2bf(f1[j]);
                    H.u[4 + j] = hb2; L.u[4 + j] = f2bf(f1[j] - bf2f(hb2));
                }
                ah[rf] = H.v; al[rf] = L.v;
            } else {
                union { bf16x8 v; uint4 q; } HH, LL;
                HH.q = make_uint4(0, 0, 0, 0); LL.q = HH.q;
                if (gr < N) {
                    size_t off = (size_t)gr * 128 + ks * 32 + koff;
                    HH.q = *reinterpret_cast<const uint4*>(AHg + off);
                    LL.q = *reinterpret_cast<const uint4*>(ALg + off);
                }
                ah[rf] = HH.v; al[rf] = LL.v;
            }
        }
    };

    f32x4 acc[4][RF];
#pragma unroll
    for (int c = 0; c < 4; c++)
#pragma unroll
        for (int r = 0; r < RF; r++) acc[c][r] = (f32x4){0.f, 0.f, 0.f, 0.f};

    bf16x8 ahA[RF], alA[RF], ahB[RF], alB[RF];
    loadA(0, ahA, alA);
    __syncthreads();   // W slice visible

#pragma unroll
    for (int ks = 0; ks < 4; ks++) {
        bf16x8* ah = (ks & 1) ? ahB : ahA;
        bf16x8* al = (ks & 1) ? alB : alA;
        if (ks < 3) loadA(ks + 1, (ks & 1) ? ahA : ahB, (ks & 1) ? alA : alB);
#pragma unroll
        for (int ct = 0; ct < 4; ct++) {
            int off = (ct * 4 + ks) * 512 + lane * 8;
            bf16x8 bh = *reinterpret_cast<const bf16x8*>(&Blds[off]);
            bf16x8 bl = *reinterpret_cast<const bf16x8*>(&Blds[8192 + off]);
#pragma unroll
            for (int rf = 0; rf < RF; rf++) {
                acc[ct][rf] = __builtin_amdgcn_mfma_f32_16x16x32_bf16(ah[rf], bh, acc[ct][rf], 0, 0, 0);
                acc[ct][rf] = __builtin_amdgcn_mfma_f32_16x16x32_bf16(al[rf], bh, acc[ct][rf], 0, 0, 0);
                acc[ct][rf] = __builtin_amdgcn_mfma_f32_16x16x32_bf16(ah[rf], bl, acc[ct][rf], 0, 0, 0);
            }
        }
    }

    // epilogue: C/D layout col=lane&15, row=(lane>>4)*4+reg
#pragma unroll
    for (int ct = 0; ct < 4; ct++) {
        int col = (ct0 + ct) * 16 + mcol;
        float bv = bb[col];
#pragma unroll
        for (int rf = 0; rf < RF; rf++) {
#pragma unroll
            for (int r = 0; r < 4; r++) {
                int gr = row0 + rf * 16 + (lane >> 4) * 4 + r;
                if (gr >= N) continue;
                float v = acc[ct][rf][r] + bv;
                if (EPI == 0) {
                    v = gelu_erf(v);
                    unsigned short hb = f2bf(v);
                    o1hi[(size_t)gr * C + col] = hb;
                    o1lo[(size_t)gr * C + col] = f2bf(v - bf2f(hb));
                } else {
                    if (wsel == 0) outq[(size_t)gr * C + col] = v;
                    else           outp[(size_t)gr * C + col] = f2bf(v);
                }
            }
        }
    }
}

// ---------------- CSR build --------------------------------------------------
__global__ __launch_bounds__(256) void hist_kernel(const int* __restrict__ dst,
                                                   int* __restrict__ cnt, int E)
{
    int i = blockIdx.x * 256 + threadIdx.x;
    if (i < E) atomicAdd(&cnt[dst[i]], 1);
}

__global__ __launch_bounds__(256) void scan1_kernel(const int* __restrict__ cnt,
                                                    int* __restrict__ offs,
                                                    int* __restrict__ bsum, int N)
{
    __shared__ int lds[256];
    int t = threadIdx.x;
    int i = blockIdx.x * 256 + t;
    int v = (i < N) ? cnt[i] : 0;
    lds[t] = v;
    __syncthreads();
    int x = v;
    for (int off = 1; off < 256; off <<= 1) {
        int y = (t >= off) ? lds[t - off] : 0;
        __syncthreads();
        x += y;
        lds[t] = x;
        __syncthreads();
    }
    if (i < N) offs[i] = x - v;
    if (t == 255) bsum[blockIdx.x] = x;
}

__global__ __launch_bounds__(256) void scan2_kernel(int* __restrict__ bsum, int NB)
{
    __shared__ int lds[256];
    int t = threadIdx.x;
    int v = (t < NB) ? bsum[t] : 0;
    lds[t] = v;
    __syncthreads();
    int x = v;
    for (int off = 1; off < 256; off <<= 1) {
        int y = (t >= off) ? lds[t - off] : 0;
        __syncthreads();
        x += y;
        lds[t] = x;
        __syncthreads();
    }
    if (t < NB) bsum[t] = x - v;
}

__global__ __launch_bounds__(256) void scan3_kernel(int* __restrict__ offs,
                                                    const int* __restrict__ bsum,
                                                    int* __restrict__ cursor,
                                                    int N, int E)
{
    int i = blockIdx.x * 256 + threadIdx.x;
    if (i < N) {
        int o = offs[i] + bsum[blockIdx.x];
        offs[i] = o;
        cursor[i] = o;
    }
    if (i == 0) offs[N] = E;
}

__global__ __launch_bounds__(256) void scatter_kernel(const int* __restrict__ src,
                                                      const int* __restrict__ dst,
                                                      int* __restrict__ cursor,
                                                      int* __restrict__ csr_src, int E)
{
    int i = blockIdx.x * 256 + threadIdx.x;
    if (i < E) {
        int d = dst[i];
        int pos = atomicAdd(&cursor[d], 1);
        csr_src[pos] = src[i];
    }
}

// ---------------- fused GAT edge-softmax + aggregation -----------------------
// One wave per dst node (wave-uniform via readfirstlane -> scalar CSR walk).
// p is bf16: D=128 -> packed dword per lane (dims 2*lane, 2*lane+1);
//            D=64  -> ushort per lane.
// EPI 0 (D=128): m2 = gelu(h+bvec) packed hi/lo bf16.  EPI 1 (D=64): fp32 out.
template <int D, int EPI>
__global__ __launch_bounds__(256) void gat_agg(
    const float* __restrict__ q, const void* __restrict__ pv_,
    const float* __restrict__ a, const float* __restrict__ bvec,
    const int* __restrict__ offs, const int* __restrict__ csr_src,
    float* __restrict__ out, unsigned int* __restrict__ mhi,
    unsigned int* __restrict__ mlo, int N)
{
    constexpr int VPL = D / 64;  // 2 (D=128) or 1 (D=64)
    const int lane = threadIdx.x & 63;
    const int node = __builtin_amdgcn_readfirstlane(blockIdx.x * 4 + (threadIdx.x >> 6));
    if (node >= N) return;  // scalar branch

    const unsigned int* pp32 = (const unsigned int*)pv_;
    const unsigned short* pp16 = (const unsigned short*)pv_;

    float qv[VPL], av[VPL], acc[VPL];
#pragma unroll
    for (int v = 0; v < VPL; v++) {
        qv[v] = q[(size_t)node * D + lane * VPL + v];
        av[v] = a[lane * VPL + v];
        acc[v] = 0.f;
    }
    float denom = 0.f;

    const int e0 = offs[node], e1 = offs[node + 1];
    int e = e0;

    for (; e + 4 <= e1; e += 4) {
        int s0 = csr_src[e + 0];
        int s1 = csr_src[e + 1];
        int s2 = csr_src[e + 2];
        int s3 = csr_src[e + 3];
        float pv0[VPL], pv1[VPL], pv2[VPL], pv3[VPL];
        if (VPL == 2) {
            unsigned int u0 = pp32[(size_t)s0 * 64 + lane];
            unsigned int u1 = pp32[(size_t)s1 * 64 + lane];
            unsigned int u2 = pp32[(size_t)s2 * 64 + lane];
            unsigned int u3 = pp32[(size_t)s3 * 64 + lane];
            pv0[0] = __uint_as_float(u0 << 16); pv0[1] = __uint_as_float(u0 & 0xffff0000u);
            pv1[0] = __uint_as_float(u1 << 16); pv1[1] = __uint_as_float(u1 & 0xffff0000u);
            pv2[0] = __uint_as_float(u2 << 16); pv2[1] = __uint_as_float(u2 & 0xffff0000u);
            pv3[0] = __uint_as_float(u3 << 16); pv3[1] = __uint_as_float(u3 & 0xffff0000u);
        } else {
            pv0[0] = bf2f(pp16[(size_t)s0 * 64 + lane]);
            pv1[0] = bf2f(pp16[(size_t)s1 * 64 + lane]);
            pv2[0] = bf2f(pp16[(size_t)s2 * 64 + lane]);
            pv3[0] = bf2f(pp16[(size_t)s3 * 64 + lane]);
        }
        float pa0 = 0.f, pa1 = 0.f, pa2 = 0.f, pa3 = 0.f;
#pragma unroll
        for (int v = 0; v < VPL; v++) {
            float t0 = qv[v] + pv0[v];
            float t1 = qv[v] + pv1[v];
            float t2 = qv[v] + pv2[v];
            float t3 = qv[v] + pv3[v];
            t0 = fmaxf(t0, SLOPE * t0);
            t1 = fmaxf(t1, SLOPE * t1);
            t2 = fmaxf(t2, SLOPE * t2);
            t3 = fmaxf(t3, SLOPE * t3);
            pa0 = fmaf(t0, av[v], pa0);
            pa1 = fmaf(t1, av[v], pa1);
            pa2 = fmaf(t2, av[v], pa2);
            pa3 = fmaf(t3, av[v], pa3);
        }
        float w0 = wave_sum_bcast(pa0);
        float w1 = wave_sum_bcast(pa1);
        float w2 = wave_sum_bcast(pa2);
        float w3 = wave_sum_bcast(pa3);
        float es0 = __expf(w0);
        float es1 = __expf(w1);
        float es2 = __expf(w2);
        float es3 = __expf(w3);
        denom += (es0 + es1) + (es2 + es3);
#pragma unroll
        for (int v = 0; v < VPL; v++) {
            acc[v] = fmaf(es0, pv0[v], acc[v]);
            acc[v] = fmaf(es1, pv1[v], acc[v]);
            acc[v] = fmaf(es2, pv2[v], acc[v]);
            acc[v] = fmaf(es3, pv3[v], acc[v]);
        }
    }
    for (; e < e1; e++) {
        int s0 = csr_src[e];
        float pv0[VPL];
        if (VPL == 2) {
            unsigned int u0 = pp32[(size_t)s0 * 64 + lane];
            pv0[0] = __uint_as_float(u0 << 16);
            pv0[1] = __uint_as_float(u0 & 0xffff0000u);
        } else {
            pv0[0] = bf2f(pp16[(size_t)s0 * 64 + lane]);
        }
        float pa0 = 0.f;
#pragma unroll
        for (int v = 0; v < VPL; v++) {
            float t0 = qv[v] + pv0[v];
            t0 = fmaxf(t0, SLOPE * t0);
            pa0 = fmaf(t0, av[v], pa0);
        }
        float es0 = __expf(wave_sum_bcast(pa0));
        denom += es0;
#pragma unroll
        for (int v = 0; v < VPL; v++)
            acc[v] = fmaf(es0, pv0[v], acc[v]);
    }

    float inv = (denom != 0.f) ? 1.f / denom : 0.f;  // zero-degree -> agg = 0
    if (EPI == 0) {
        float g0 = gelu_erf(acc[0] * inv + bvec[lane * 2 + 0]);
        float g1 = gelu_erf(acc[1] * inv + bvec[lane * 2 + 1]);
        unsigned short h0 = f2bf(g0), h1 = f2bf(g1);
        unsigned short l0 = f2bf(g0 - bf2f(h0)), l1 = f2bf(g1 - bf2f(h1));
        mhi[(size_t)node * 64 + lane] = (unsigned int)h0 | ((unsigned int)h1 << 16);
        mlo[(size_t)node * 64 + lane] = (unsigned int)l0 | ((unsigned int)l1 << 16);
    } else {
        out[(size_t)node * D + lane] = acc[0] * inv + bvec[lane];
    }
}

// ---------------- launch ------------------------------------------------------
extern "C" void kernel_launch(void* const* d_in, const int* in_sizes, int n_in,
                              void* d_out, int out_size, void* d_ws, size_t ws_size,
                              hipStream_t stream)
{
    const float* x     = (const float*)d_in[0];
    const float* W0    = (const float*)d_in[1];
    const float* b0    = (const float*)d_in[2];
    const float* Wq1   = (const float*)d_in[3];
    const float* bq1   = (const float*)d_in[4];
    const float* Wp1   = (const float*)d_in[5];
    const float* bp1   = (const float*)d_in[6];
    const float* a1    = (const float*)d_in[7];
    const float* bg2   = (const float*)d_in[8];
    const float* Wq2   = (const float*)d_in[9];
    const float* bq2   = (const float*)d_in[10];
    const float* Wp2   = (const float*)d_in[11];
    const float* bp2   = (const float*)d_in[12];
    const float* a2    = (const float*)d_in[13];
    const float* b_out = (const float*)d_in[14];
    const int*   src   = (const int*)d_in[15];
    const int*   dst   = (const int*)d_in[16];

    const int N = in_sizes[0] / 128;
    const int E = in_sizes[15];
    float* out = (float*)d_out;

    // workspace carve
    float* q_buf        = (float*)d_ws;                      // N*128 f32
    unsigned short* pb  = (unsigned short*)(q_buf + (size_t)N * 128);  // N*128 bf16
    unsigned short* Mhi = pb + (size_t)N * 128;
    unsigned short* Mlo = Mhi + (size_t)N * 128;
    unsigned short* P0  = Mlo + (size_t)N * 128;
    unsigned short* Pq1 = P0  + 128 * 128 * 2;
    unsigned short* Pp1 = Pq1 + 128 * 128 * 2;
    unsigned short* Pq2 = Pp1 + 128 * 128 * 2;
    unsigned short* Pp2 = Pq2 + 128 * 64 * 2;
    int* offs    = (int*)(Pp2 + 128 * 64 * 2);
    int* cursor  = offs + (N + 1);
    int* csr_src = cursor + N;
    int* bsum    = csr_src + E;

    const int NB = (N + 255) / 256;   // <= 256 assumed (N <= 65536)

    // 1) weight prepack + cursor zero
    pack_w<<<dim3(64, 6), 256, 0, stream>>>(W0, Wq1, Wp1, Wq2, Wp2,
                                            P0, Pq1, Pp1, Pq2, Pp2, cursor, N);
    // 2-5) CSR build (hierarchical parallel scan)
    hist_kernel<<<(E + 255) / 256, 256, 0, stream>>>(dst, cursor, E);
    scan1_kernel<<<NB, 256, 0, stream>>>(cursor, offs, bsum, N);
    scan2_kernel<<<1, 256, 0, stream>>>(bsum, NB);
    scan3_kernel<<<NB, 256, 0, stream>>>(offs, bsum, cursor, N, E);
    scatter_kernel<<<(E + 255) / 256, 256, 0, stream>>>(src, dst, cursor, csr_src, E);

    const int GB = (N + 255) / 256;

    // 6) layer 0: m1 = gelu(x@W0 + b0) -> Mhi/Mlo
    mfma_gemm<128, 2, 0><<<dim3(GB, 2), 256, 0, stream>>>(
        x, nullptr, nullptr, P0, b0, nullptr, nullptr,
        nullptr, nullptr, Mhi, Mlo, N);
    // 7) layer 1 projections: q1 fp32, p1 bf16
    mfma_gemm<128, 4, 1><<<dim3(GB, 4), 256, 0, stream>>>(
        nullptr, Mhi, Mlo, Pq1, bq1, Pp1, bp1,
        q_buf, pb, nullptr, nullptr, N);
    // 8) layer 1 GAT -> m2 = gelu(h1 + bg2) -> Mhi/Mlo
    gat_agg<128, 0><<<(N + 3) / 4, 256, 0, stream>>>(
        q_buf, pb, a1, bg2, offs, csr_src,
        nullptr, (unsigned int*)Mhi, (unsigned int*)Mlo, N);
    // 9) layer 2 projections: q2 fp32, p2 bf16
    mfma_gemm<64, 2, 1><<<dim3(GB, 2), 256, 0, stream>>>(
        nullptr, Mhi, Mlo, Pq2, bq2, Pp2, bp2,
        q_buf, pb, nullptr, nullptr, N);
    // 10) layer 2 GAT + b_out -> d_out
    gat_agg<64, 1><<<(N + 3) / 4, 256, 0, stream>>>(
        q_buf, pb, a2, b_out, offs, csr_src,
        out, nullptr, nullptr, N);
}

// Round 10
// 336.306 us; speedup vs baseline: 1.4254x; 1.1061x over previous
//
#include <hip/hip_runtime.h>
#include <hip/hip_bf16.h>
#include <math.h>

// GAT 2-layer fused pipeline for MI355X (gfx950).
// Dims per reference: D_IN=D_H=128, D_OUT=64, SLOPE=0.2.
//
// Round-10: CSR build rewritten as atomic-free two-level counting sort.
// r9's scatter was bound by 52 MB of partial-line HBM write-backs (every
// 4B scattered store -> own 64B line; WRITE_SIZE == 64B*E exactly) plus
// 800k device-scope atomics in hist. New pipeline:
//   hist_coarse (LDS hist over dst>>4 bins) -> 3-kernel parallel scan ->
//   scatter_coarse (LDS cursors, pairs grouped by coarse bin; ~64B runs) ->
//   finalize (one block per 16-node bin: 16-bit packed LDS hist+rank,
//   contiguous csr_src writes, offs written directly). Zero global atomics.
// pairs buffer aliases q_buf (dead until gemm-1).
// GEMMs (split-precision bf16 MFMA, LDS-resident W slices) and gat_agg
// (scalar CSR walk, bf16 p gather, DPP reduce) unchanged from round 9.

#define SLOPE 0.2f

typedef __attribute__((ext_vector_type(8))) __bf16 bf16x8;
typedef __attribute__((ext_vector_type(4))) float f32x4;

__device__ __forceinline__ float gelu_erf(float x) {
    return 0.5f * x * (1.0f + erff(x * 0.70710678118654752f));
}

__device__ __forceinline__ unsigned short f2bf(float f) {  // RNE
    unsigned int u = __float_as_uint(f);
    return (unsigned short)((u + 0x7fffu + ((u >> 16) & 1u)) >> 16);
}
__device__ __forceinline__ float bf2f(unsigned short h) {
    return __uint_as_float((unsigned int)h << 16);
}

// Full-wave (64-lane) f32 sum via DPP; result broadcast via readlane 63.
__device__ __forceinline__ float wave_sum_bcast(float x) {
    x += __int_as_float(__builtin_amdgcn_update_dpp(0, __float_as_int(x), 0x111, 0xF, 0xF, true));
    x += __int_as_float(__builtin_amdgcn_update_dpp(0, __float_as_int(x), 0x112, 0xF, 0xF, true));
    x += __int_as_float(__builtin_amdgcn_update_dpp(0, __float_as_int(x), 0x114, 0xF, 0xF, true));
    x += __int_as_float(__builtin_amdgcn_update_dpp(0, __float_as_int(x), 0x118, 0xF, 0xF, true));
    x += __int_as_float(__builtin_amdgcn_update_dpp(0, __float_as_int(x), 0x142, 0xF, 0xF, true));
    x += __int_as_float(__builtin_amdgcn_update_dpp(0, __float_as_int(x), 0x143, 0xF, 0xF, true));
    return __int_as_float(__builtin_amdgcn_readlane(__float_as_int(x), 63));
}

// ---------------- weight prepack ---------------------------------------------
// Pack index i = ((ct*4+ks)*64 + lane)*8 + j  ->  W[k][n],
// k = ks*32 + (lane>>4)*8 + j,  n = ct*16 + (lane&15).  hi at [i], lo at [CE+i].
__global__ __launch_bounds__(256) void pack_w(
    const float* __restrict__ W0,  const float* __restrict__ Wq1,
    const float* __restrict__ Wp1, const float* __restrict__ Wq2,
    const float* __restrict__ Wp2,
    unsigned short* __restrict__ P0,  unsigned short* __restrict__ Pq1,
    unsigned short* __restrict__ Pp1, unsigned short* __restrict__ Pq2,
    unsigned short* __restrict__ Pp2)
{
    const float* W; unsigned short* P; int C;
    switch (blockIdx.y) {
        case 0:  W = W0;  P = P0;  C = 128; break;
        case 1:  W = Wq1; P = Pq1; C = 128; break;
        case 2:  W = Wp1; P = Pp1; C = 128; break;
        case 3:  W = Wq2; P = Pq2; C = 64;  break;
        default: W = Wp2; P = Pp2; C = 64;  break;
    }
    int i = blockIdx.x * 256 + threadIdx.x;
    int CE = C * 128;
    if (i >= CE) return;
    int j = i & 7, l = (i >> 3) & 63, ks = (i >> 9) & 3, ct = i >> 11;
    int k = ks * 32 + ((l >> 4) << 3) + j;
    int n = ct * 16 + (l & 15);
    float v = W[k * C + n];
    unsigned short hb = f2bf(v);
    P[i] = hb;
    P[CE + i] = f2bf(v - bf2f(hb));
}

// ---------------- MFMA GEMM -------------------------------------------------
// out[N,C] = act(A[N,128] @ W[128,C] + bias); block = 256 rows x 64 cols.
// gridDim.y pieces; each stages a 32 KB W slice (4 col-tiles, hi+lo) in LDS.
// EPI 0: out = gelu -> hi/lo packed bf16 (layer 0).
// EPI 1: piece wsel==0 -> q fp32; wsel==1 -> p bf16.
template <int C, int PIECES, int EPI>
__global__ __launch_bounds__(256) void mfma_gemm(
    const float* __restrict__ Af,
    const unsigned short* __restrict__ AHg, const unsigned short* __restrict__ ALg,
    const unsigned short* __restrict__ P1, const float* __restrict__ b1,
    const unsigned short* __restrict__ P2, const float* __restrict__ b2,
    float* __restrict__ outq, unsigned short* __restrict__ outp,
    unsigned short* __restrict__ o1hi, unsigned short* __restrict__ o1lo,
    int N)
{
    constexpr bool AF32 = (EPI == 0);
    constexpr int CE = C * 128;
    constexpr int RF = 4;

    int wsel, ct0;
    if constexpr (PIECES == 4)      { wsel = blockIdx.y >> 1; ct0 = (blockIdx.y & 1) * 4; }
    else if constexpr (C == 128)    { wsel = 0; ct0 = blockIdx.y * 4; }
    else                            { wsel = blockIdx.y; ct0 = 0; }

    const unsigned short* Pw = wsel ? P2 : P1;
    const float* bb = wsel ? b2 : b1;
    const unsigned short* Whi = Pw + ct0 * 2048;
    const unsigned short* Wlo = Pw + CE + ct0 * 2048;

    __shared__ __align__(16) unsigned short Blds[16384];  // 4 ct x (hi+lo) = 32 KB

    const int t = threadIdx.x;
    const int lane = t & 63;
    const int w = t >> 6;
    const int row0 = blockIdx.x * 256 + w * 64;
    const int mcol = lane & 15;
    const int koff = (lane >> 4) * 8;

#pragma unroll
    for (int i = 0; i < 4; i++) {
        int idx = (t + i * 256) * 8;
        *reinterpret_cast<uint4*>(&Blds[idx]) = *reinterpret_cast<const uint4*>(&Whi[idx]);
        *reinterpret_cast<uint4*>(&Blds[8192 + idx]) = *reinterpret_cast<const uint4*>(&Wlo[idx]);
    }

    auto loadA = [&](int ks, bf16x8* ah, bf16x8* al) {
#pragma unroll
        for (int rf = 0; rf < RF; rf++) {
            int gr = row0 + rf * 16 + mcol;
            if (AF32) {
                float4 v0 = make_float4(0.f, 0.f, 0.f, 0.f), v1 = v0;
                if (gr < N) {
                    const float* ap = Af + (size_t)gr * 128 + ks * 32 + koff;
                    v0 = *reinterpret_cast<const float4*>(ap);
                    v1 = *reinterpret_cast<const float4*>(ap + 4);
                }
                union { bf16x8 v; unsigned short u[8]; } H, L;
                const float* f0 = reinterpret_cast<const float*>(&v0);
                const float* f1 = reinterpret_cast<const float*>(&v1);
#pragma unroll
                for (int j = 0; j < 4; j++) {
                    unsigned short hb = f2bf(f0[j]);
                    H.u[j] = hb; L.u[j] = f2bf(f0[j] - bf2f(hb));
                    unsigned short hb2 = f2bf(f1[j]);
                    H.u[4 + j] = hb2; L.u[4 + j] = f2bf(f1[j] - bf2f(hb2));
                }
                ah[rf] = H.v; al[rf] = L.v;
            } else {
                union { bf16x8 v; uint4 q; } HH, LL;
                HH.q = make_uint4(0, 0, 0, 0); LL.q = HH.q;
                if (gr < N) {
                    size_t off = (size_t)gr * 128 + ks * 32 + koff;
                    HH.q = *reinterpret_cast<const uint4*>(AHg + off);
                    LL.q = *reinterpret_cast<const uint4*>(ALg + off);
                }
                ah[rf] = HH.v; al[rf] = LL.v;
            }
        }
    };

    f32x4 acc[4][RF];
#pragma unroll
    for (int c = 0; c < 4; c++)
#pragma unroll
        for (int r = 0; r < RF; r++) acc[c][r] = (f32x4){0.f, 0.f, 0.f, 0.f};

    bf16x8 ahA[RF], alA[RF], ahB[RF], alB[RF];
    loadA(0, ahA, alA);
    __syncthreads();   // W slice visible

#pragma unroll
    for (int ks = 0; ks < 4; ks++) {
        bf16x8* ah = (ks & 1) ? ahB : ahA;
        bf16x8* al = (ks & 1) ? alB : alA;
        if (ks < 3) loadA(ks + 1, (ks & 1) ? ahA : ahB, (ks & 1) ? alA : alB);
#pragma unroll
        for (int ct = 0; ct < 4; ct++) {
            int off = (ct * 4 + ks) * 512 + lane * 8;
            bf16x8 bh = *reinterpret_cast<const bf16x8*>(&Blds[off]);
            bf16x8 bl = *reinterpret_cast<const bf16x8*>(&Blds[8192 + off]);
#pragma unroll
            for (int rf = 0; rf < RF; rf++) {
                acc[ct][rf] = __builtin_amdgcn_mfma_f32_16x16x32_bf16(ah[rf], bh, acc[ct][rf], 0, 0, 0);
                acc[ct][rf] = __builtin_amdgcn_mfma_f32_16x16x32_bf16(al[rf], bh, acc[ct][rf], 0, 0, 0);
                acc[ct][rf] = __builtin_amdgcn_mfma_f32_16x16x32_bf16(ah[rf], bl, acc[ct][rf], 0, 0, 0);
            }
        }
    }

    // epilogue: C/D layout col=lane&15, row=(lane>>4)*4+reg
#pragma unroll
    for (int ct = 0; ct < 4; ct++) {
        int col = (ct0 + ct) * 16 + mcol;
        float bv = bb[col];
#pragma unroll
        for (int rf = 0; rf < RF; rf++) {
#pragma unroll
            for (int r = 0; r < 4; r++) {
                int gr = row0 + rf * 16 + (lane >> 4) * 4 + r;
                if (gr >= N) continue;
                float v = acc[ct][rf][r] + bv;
                if (EPI == 0) {
                    v = gelu_erf(v);
                    unsigned short hb = f2bf(v);
                    o1hi[(size_t)gr * C + col] = hb;
                    o1lo[(size_t)gr * C + col] = f2bf(v - bf2f(hb));
                } else {
                    if (wsel == 0) outq[(size_t)gr * C + col] = v;
                    else           outp[(size_t)gr * C + col] = f2bf(v);
                }
            }
        }
    }
}

// ---------------- CSR build: atomic-free two-level counting sort -------------
// Coarse bin = dst >> 4 (16 nodes per bin), CB = ceil(N/16) <= 4096.
// 64 edge-blocks; gh[bin*64 + blk] = count (bin-major for linear scan).

__global__ __launch_bounds__(256) void hist_coarse(
    const int* __restrict__ dst, int* __restrict__ gh, int E, int CB)
{
    __shared__ int cnt[4096];
    const int blk = blockIdx.x;     // 0..63
    const int t = threadIdx.x;
    for (int b = t; b < CB; b += 256) cnt[b] = 0;
    __syncthreads();
    const int epb = (E + 63) / 64;
    const int s = blk * epb;
    const int e_ = (s + epb < E) ? s + epb : E;
    for (int i = s + t; i < e_; i += 256)
        atomicAdd(&cnt[dst[i] >> 4], 1);
    __syncthreads();
    for (int b = t; b < CB; b += 256)
        gh[b * 64 + blk] = cnt[b];
}

// hierarchical exclusive scan over M = CB*64 values: gh -> gscan
__global__ __launch_bounds__(256) void scan1_kernel(const int* __restrict__ gh,
                                                    int* __restrict__ gscan,
                                                    int* __restrict__ bsum, int M)
{
    __shared__ int lds[256];
    int t = threadIdx.x;
    int i = blockIdx.x * 256 + t;
    int v = (i < M) ? gh[i] : 0;
    lds[t] = v;
    __syncthreads();
    int x = v;
    for (int off = 1; off < 256; off <<= 1) {
        int y = (t >= off) ? lds[t - off] : 0;
        __syncthreads();
        x += y;
        lds[t] = x;
        __syncthreads();
    }
    if (i < M) gscan[i] = x - v;
    if (t == 255) bsum[blockIdx.x] = x;
}

__global__ __launch_bounds__(1024) void scan2_kernel(int* __restrict__ bsum, int NB)
{
    __shared__ int lds[1024];
    int t = threadIdx.x;
    int v = (t < NB) ? bsum[t] : 0;
    lds[t] = v;
    __syncthreads();
    int x = v;
    for (int off = 1; off < 1024; off <<= 1) {
        int y = (t >= off) ? lds[t - off] : 0;
        __syncthreads();
        x += y;
        lds[t] = x;
        __syncthreads();
    }
    if (t < NB) bsum[t] = x - v;
}

__global__ __launch_bounds__(256) void scan3_kernel(int* __restrict__ gscan,
                                                    const int* __restrict__ bsum, int M)
{
    int i = blockIdx.x * 256 + threadIdx.x;
    if (i < M) gscan[i] += bsum[blockIdx.x];
}

// scatter edges into coarse-bin-grouped (dst,src) pairs; LDS cursors only.
__global__ __launch_bounds__(256) void scatter_coarse(
    const int* __restrict__ src, const int* __restrict__ dst,
    const int* __restrict__ gscan, int2* __restrict__ pairs, int E, int CB)
{
    __shared__ int cur[4096];
    const int blk = blockIdx.x;     // 0..63
    const int t = threadIdx.x;
    for (int b = t; b < CB; b += 256)
        cur[b] = gscan[b * 64 + blk];
    __syncthreads();
    const int epb = (E + 63) / 64;
    const int s = blk * epb;
    const int e_ = (s + epb < E) ? s + epb : E;
    for (int i = s + t; i < e_; i += 256) {
        int d = dst[i];
        int sv = src[i];
        int pos = atomicAdd(&cur[d >> 4], 1);   // LDS atomic
        pairs[pos] = make_int2(d, sv);
    }
}

// one block per coarse bin: exact CSR within the bin's contiguous segment.
__global__ __launch_bounds__(256) void finalize_kernel(
    const int2* __restrict__ pairs, const int* __restrict__ gscan,
    int* __restrict__ offs, int* __restrict__ csr_src, int N, int E, int CB)
{
    const int c = blockIdx.x;
    const int t = threadIdx.x;
    __shared__ unsigned int cnt[8], rnk[8];
    __shared__ int pref[16];
    if (t < 8) { cnt[t] = 0u; rnk[t] = 0u; }
    __syncthreads();

    const int s  = gscan[c * 64];
    const int e_ = (c + 1 < CB) ? gscan[(c + 1) * 64] : E;
    const int base = c * 16;

    for (int i = s + t; i < e_; i += 256) {
        int d = pairs[i].x - base;    // 0..15
        atomicAdd(&cnt[d >> 1], 1u << ((d & 1) * 16));
    }
    __syncthreads();
    if (t == 0) {
        int run = s;
        for (int j = 0; j < 16; j++) {
            pref[j] = run;
            run += (int)((cnt[j >> 1] >> ((j & 1) * 16)) & 0xffffu);
        }
    }
    __syncthreads();
    if (t < 16 && base + t < N) offs[base + t] = pref[t];
    if (c == CB - 1 && t == 0) offs[N] = E;

    for (int i = s + t; i < e_; i += 256) {
        int2 pr = pairs[i];
        int d = pr.x - base;
        unsigned int old = atomicAdd(&rnk[d >> 1], 1u << ((d & 1) * 16));
        int r = (int)((old >> ((d & 1) * 16)) & 0xffffu);
        csr_src[pref[d] + r] = pr.y;
    }
}

// ---------------- fused GAT edge-softmax + aggregation -----------------------
// One wave per dst node (wave-uniform via readfirstlane -> scalar CSR walk).
// p is bf16: D=128 -> packed dword per lane (dims 2*lane, 2*lane+1);
//            D=64  -> ushort per lane.
// EPI 0 (D=128): m2 = gelu(h+bvec) packed hi/lo bf16.  EPI 1 (D=64): fp32 out.
template <int D, int EPI>
__global__ __launch_bounds__(256) void gat_agg(
    const float* __restrict__ q, const void* __restrict__ pv_,
    const float* __restrict__ a, const float* __restrict__ bvec,
    const int* __restrict__ offs, const int* __restrict__ csr_src,
    float* __restrict__ out, unsigned int* __restrict__ mhi,
    unsigned int* __restrict__ mlo, int N)
{
    constexpr int VPL = D / 64;  // 2 (D=128) or 1 (D=64)
    const int lane = threadIdx.x & 63;
    const int node = __builtin_amdgcn_readfirstlane(blockIdx.x * 4 + (threadIdx.x >> 6));
    if (node >= N) return;  // scalar branch

    const unsigned int* pp32 = (const unsigned int*)pv_;
    const unsigned short* pp16 = (const unsigned short*)pv_;

    float qv[VPL], av[VPL], acc[VPL];
#pragma unroll
    for (int v = 0; v < VPL; v++) {
        qv[v] = q[(size_t)node * D + lane * VPL + v];
        av[v] = a[lane * VPL + v];
        acc[v] = 0.f;
    }
    float denom = 0.f;

    const int e0 = offs[node], e1 = offs[node + 1];
    int e = e0;

    for (; e + 4 <= e1; e += 4) {
        int s0 = csr_src[e + 0];
        int s1 = csr_src[e + 1];
        int s2 = csr_src[e + 2];
        int s3 = csr_src[e + 3];
        float pv0[VPL], pv1[VPL], pv2[VPL], pv3[VPL];
        if (VPL == 2) {
            unsigned int u0 = pp32[(size_t)s0 * 64 + lane];
            unsigned int u1 = pp32[(size_t)s1 * 64 + lane];
            unsigned int u2 = pp32[(size_t)s2 * 64 + lane];
            unsigned int u3 = pp32[(size_t)s3 * 64 + lane];
            pv0[0] = __uint_as_float(u0 << 16); pv0[1] = __uint_as_float(u0 & 0xffff0000u);
            pv1[0] = __uint_as_float(u1 << 16); pv1[1] = __uint_as_float(u1 & 0xffff0000u);
            pv2[0] = __uint_as_float(u2 << 16); pv2[1] = __uint_as_float(u2 & 0xffff0000u);
            pv3[0] = __uint_as_float(u3 << 16); pv3[1] = __uint_as_float(u3 & 0xffff0000u);
        } else {
            pv0[0] = bf2f(pp16[(size_t)s0 * 64 + lane]);
            pv1[0] = bf2f(pp16[(size_t)s1 * 64 + lane]);
            pv2[0] = bf2f(pp16[(size_t)s2 * 64 + lane]);
            pv3[0] = bf2f(pp16[(size_t)s3 * 64 + lane]);
        }
        float pa0 = 0.f, pa1 = 0.f, pa2 = 0.f, pa3 = 0.f;
#pragma unroll
        for (int v = 0; v < VPL; v++) {
            float t0 = qv[v] + pv0[v];
            float t1 = qv[v] + pv1[v];
            float t2 = qv[v] + pv2[v];
            float t3 = qv[v] + pv3[v];
            t0 = fmaxf(t0, SLOPE * t0);
            t1 = fmaxf(t1, SLOPE * t1);
            t2 = fmaxf(t2, SLOPE * t2);
            t3 = fmaxf(t3, SLOPE * t3);
            pa0 = fmaf(t0, av[v], pa0);
            pa1 = fmaf(t1, av[v], pa1);
            pa2 = fmaf(t2, av[v], pa2);
            pa3 = fmaf(t3, av[v], pa3);
        }
        float w0 = wave_sum_bcast(pa0);
        float w1 = wave_sum_bcast(pa1);
        float w2 = wave_sum_bcast(pa2);
        float w3 = wave_sum_bcast(pa3);
        float es0 = __expf(w0);
        float es1 = __expf(w1);
        float es2 = __expf(w2);
        float es3 = __expf(w3);
        denom += (es0 + es1) + (es2 + es3);
#pragma unroll
        for (int v = 0; v < VPL; v++) {
            acc[v] = fmaf(es0, pv0[v], acc[v]);
            acc[v] = fmaf(es1, pv1[v], acc[v]);
            acc[v] = fmaf(es2, pv2[v], acc[v]);
            acc[v] = fmaf(es3, pv3[v], acc[v]);
        }
    }
    for (; e < e1; e++) {
        int s0 = csr_src[e];
        float pv0[VPL];
        if (VPL == 2) {
            unsigned int u0 = pp32[(size_t)s0 * 64 + lane];
            pv0[0] = __uint_as_float(u0 << 16);
            pv0[1] = __uint_as_float(u0 & 0xffff0000u);
        } else {
            pv0[0] = bf2f(pp16[(size_t)s0 * 64 + lane]);
        }
        float pa0 = 0.f;
#pragma unroll
        for (int v = 0; v < VPL; v++) {
            float t0 = qv[v] + pv0[v];
            t0 = fmaxf(t0, SLOPE * t0);
            pa0 = fmaf(t0, av[v], pa0);
        }
        float es0 = __expf(wave_sum_bcast(pa0));
        denom += es0;
#pragma unroll
        for (int v = 0; v < VPL; v++)
            acc[v] = fmaf(es0, pv0[v], acc[v]);
    }

    float inv = (denom != 0.f) ? 1.f / denom : 0.f;  // zero-degree -> agg = 0
    if (EPI == 0) {
        float g0 = gelu_erf(acc[0] * inv + bvec[lane * 2 + 0]);
        float g1 = gelu_erf(acc[1] * inv + bvec[lane * 2 + 1]);
        unsigned short h0 = f2bf(g0), h1 = f2bf(g1);
        unsigned short l0 = f2bf(g0 - bf2f(h0)), l1 = f2bf(g1 - bf2f(h1));
        mhi[(size_t)node * 64 + lane] = (unsigned int)h0 | ((unsigned int)h1 << 16);
        mlo[(size_t)node * 64 + lane] = (unsigned int)l0 | ((unsigned int)l1 << 16);
    } else {
        out[(size_t)node * D + lane] = acc[0] * inv + bvec[lane];
    }
}

// ---------------- launch ------------------------------------------------------
extern "C" void kernel_launch(void* const* d_in, const int* in_sizes, int n_in,
                              void* d_out, int out_size, void* d_ws, size_t ws_size,
                              hipStream_t stream)
{
    const float* x     = (const float*)d_in[0];
    const float* W0    = (const float*)d_in[1];
    const float* b0    = (const float*)d_in[2];
    const float* Wq1   = (const float*)d_in[3];
    const float* bq1   = (const float*)d_in[4];
    const float* Wp1   = (const float*)d_in[5];
    const float* bp1   = (const float*)d_in[6];
    const float* a1    = (const float*)d_in[7];
    const float* bg2   = (const float*)d_in[8];
    const float* Wq2   = (const float*)d_in[9];
    const float* bq2   = (const float*)d_in[10];
    const float* Wp2   = (const float*)d_in[11];
    const float* bp2   = (const float*)d_in[12];
    const float* a2    = (const float*)d_in[13];
    const float* b_out = (const float*)d_in[14];
    const int*   src   = (const int*)d_in[15];
    const int*   dst   = (const int*)d_in[16];

    const int N = in_sizes[0] / 128;
    const int E = in_sizes[15];
    float* out = (float*)d_out;

    // workspace carve
    float* q_buf        = (float*)d_ws;                      // N*128 f32
    unsigned short* pb  = (unsigned short*)(q_buf + (size_t)N * 128);  // N*128 bf16
    unsigned short* Mhi = pb + (size_t)N * 128;
    unsigned short* Mlo = Mhi + (size_t)N * 128;
    unsigned short* P0  = Mlo + (size_t)N * 128;
    unsigned short* Pq1 = P0  + 128 * 128 * 2;
    unsigned short* Pp1 = Pq1 + 128 * 128 * 2;
    unsigned short* Pq2 = Pp1 + 128 * 128 * 2;
    unsigned short* Pp2 = Pq2 + 128 * 64 * 2;
    int* offs    = (int*)(Pp2 + 128 * 64 * 2);
    int* csr_src = offs + (N + 2);
    const int CB = (N + 15) / 16;          // coarse bins (<= 4096 for N<=65536)
    const int M  = CB * 64;
    int* gh    = csr_src + E;
    int* gscan = gh + M;
    int* bsum  = gscan + M;                // 1024 ints
    // pairs aliases q_buf (dead until gemm layer-1); int2-aligned (base of ws)
    int2* pairs = (int2*)q_buf;

    const int NB1 = (M + 255) / 256;       // <= 1024

    // 1) weight prepack
    pack_w<<<dim3(64, 5), 256, 0, stream>>>(W0, Wq1, Wp1, Wq2, Wp2,
                                            P0, Pq1, Pp1, Pq2, Pp2);
    // 2-7) CSR build (atomic-free two-level counting sort)
    hist_coarse<<<64, 256, 0, stream>>>(dst, gh, E, CB);
    scan1_kernel<<<NB1, 256, 0, stream>>>(gh, gscan, bsum, M);
    scan2_kernel<<<1, 1024, 0, stream>>>(bsum, NB1);
    scan3_kernel<<<NB1, 256, 0, stream>>>(gscan, bsum, M);
    scatter_coarse<<<64, 256, 0, stream>>>(src, dst, gscan, pairs, E, CB);
    finalize_kernel<<<CB, 256, 0, stream>>>(pairs, gscan, offs, csr_src, N, E, CB);

    const int GB = (N + 255) / 256;

    // 8) layer 0: m1 = gelu(x@W0 + b0) -> Mhi/Mlo
    mfma_gemm<128, 2, 0><<<dim3(GB, 2), 256, 0, stream>>>(
        x, nullptr, nullptr, P0, b0, nullptr, nullptr,
        nullptr, nullptr, Mhi, Mlo, N);
    // 9) layer 1 projections: q1 fp32, p1 bf16
    mfma_gemm<128, 4, 1><<<dim3(GB, 4), 256, 0, stream>>>(
        nullptr, Mhi, Mlo, Pq1, bq1, Pp1, bp1,
        q_buf, pb, nullptr, nullptr, N);
    // 10) layer 1 GAT -> m2 = gelu(h1 + bg2) -> Mhi/Mlo
    gat_agg<128, 0><<<(N + 3) / 4, 256, 0, stream>>>(
        q_buf, pb, a1, bg2, offs, csr_src,
        nullptr, (unsigned int*)Mhi, (unsigned int*)Mlo, N);
    // 11) layer 2 projections: q2 fp32, p2 bf16
    mfma_gemm<64, 2, 1><<<dim3(GB, 2), 256, 0, stream>>>(
        nullptr, Mhi, Mlo, Pq2, bq2, Pp2, bp2,
        q_buf, pb, nullptr, nullptr, N);
    // 12) layer 2 GAT + b_out -> d_out
    gat_agg<64, 1><<<(N + 3) / 4, 256, 0, stream>>>(
        q_buf, pb, a2, b_out, offs, csr_src,
        out, nullptr, nullptr, N);
}